// Round 1
// 371.547 us; speedup vs baseline: 1.1126x; 1.1126x over previous
//
#include <hip/hip_runtime.h>

// MHA forward: x(2,2048,2048) fp32, Wq/Wk/Wv/Wo (2048,2048) fp32 -> out fp32.
// R4: both GEMMs rewritten as 512-thread BM256xBN128xBK64 with 3-deep LDS ring
//     and counted vmcnt(6) pipeline (T3+T4): one raw s_barrier per K-tile,
//     loads stay in flight across barriers. QKV fused into one N=6144 GEMM
//     (768 blocks = 3 full CU-waves). RoPE sincos precomputed into a table;
//     Wq/Wk rows permuted within-head so RoPE pairs are adjacent fragments.
//     Attention kernel unchanged from R3.

#define SEQ 2048
#define DMODEL 2048
#define NH 16
#define HD 128

typedef __attribute__((ext_vector_type(8))) short bf16x8;  // 8 bf16 = 4 VGPRs
typedef __attribute__((ext_vector_type(4))) float f32x4;

__device__ __forceinline__ unsigned short f2bf(float f) {  // RNE fp32->bf16
  unsigned int u = __float_as_uint(f);
  u += 0x7fffu + ((u >> 16) & 1u);
  return (unsigned short)(u >> 16);
}

__device__ __forceinline__ void g2l16(const void* g, void* l) {
  __builtin_amdgcn_global_load_lds((const __attribute__((address_space(1))) void*)g,
                                   (__attribute__((address_space(3))) void*)l,
                                   16, 0, 0);
}

__device__ __forceinline__ f32x4 mfma16(bf16x8 a, bf16x8 b, f32x4 c) {
  return __builtin_amdgcn_mfma_f32_16x16x32_bf16(a, b, c, 0, 0, 0);
}

template <int CTRL>
__device__ __forceinline__ float dpp_ror(float v) {
  return __int_as_float(__builtin_amdgcn_mov_dpp(__float_as_int(v), CTRL, 0xf, 0xf, false));
}
__device__ __forceinline__ float red_max16(float v) {
  v = fmaxf(v, dpp_ror<0x128>(v));
  v = fmaxf(v, dpp_ror<0x124>(v));
  v = fmaxf(v, dpp_ror<0x122>(v));
  v = fmaxf(v, dpp_ror<0x121>(v));
  return v;
}
__device__ __forceinline__ float red_sum16(float v) {
  v += dpp_ror<0x128>(v);
  v += dpp_ror<0x124>(v);
  v += dpp_ror<0x122>(v);
  v += dpp_ror<0x121>(v);
  return v;
}

// one launch: converts x + all four weights to bf16, permutes Wq/Wk rows
// within-head (RoPE pairs -> adjacent 16-col fragments), fills rope table.
// Permutation (head-local output feature o in [0,128)):
//   e = ((o>>4)&3)*32 + ((o>>6)&1)*16 + (o&15)
// so orig pair (d, d+64) lands at new cols (q*32+r, q*32+16+r), q=d>>4, r=d&15.
__global__ __launch_bounds__(256) void cvt_all(const float* __restrict__ x,
                                               const float* __restrict__ wq,
                                               const float* __restrict__ wk,
                                               const float* __restrict__ wv,
                                               const float* __restrict__ wo,
                                               unsigned short* __restrict__ dst0,
                                               float2* __restrict__ rtab) {
  const int b = blockIdx.x;
  if (b >= 24576) {  // rope cos/sin table: 2048 x 64
    const int idx = (b - 24576) * 256 + threadIdx.x;  // [0, 131072)
    const int s = idx >> 6, d = idx & 63;
    float sn, cs;
    sincosf((float)s * exp2f(-0.20762050593046f * (float)d), &sn, &cs);
    rtab[idx] = make_float2(cs, sn);
    return;
  }
  const float* src;
  unsigned short* dst;
  int idx, r = -1;
  if (b < 8192) {  // x: 2097152 float4's
    src = x; dst = dst0; idx = b * 256 + threadIdx.x;
  } else {
    r = (b - 8192) >> 12;  // 4096 blocks per weight
    src = (r == 0) ? wq : (r == 1) ? wk : (r == 2) ? wv : wo;
    dst = dst0 + (size_t)2 * SEQ * DMODEL + (size_t)r * DMODEL * DMODEL;
    idx = ((b - 8192) & 4095) * 256 + threadIdx.x;
  }
  const float4 v = ((const float4*)src)[idx];
  ushort4 o;
  o.x = f2bf(v.x); o.y = f2bf(v.y); o.z = f2bf(v.z); o.w = f2bf(v.w);
  int widx = idx;
  if (r == 0 || r == 1) {  // permute Wq/Wk output-feature rows within head
    const int row = idx >> 9, col = idx & 511;
    const int o_ = row & 127;
    const int e = (((o_ >> 4) & 3) << 5) | (((o_ >> 6) & 1) << 4) | (o_ & 15);
    widx = (((row & ~127) | e) << 9) | col;
  }
  ((ushort4*)dst)[widx] = o;
}

// ---------------------------------------------------------------------------
// Pipelined GEMM core: C[m,n] = sum_k A[m,k]*B[n,k].
// BM=256, BN=128, BK=64. 512 threads = 8 waves (4M x 2N), wave tile 64x64.
// LDS: ring of 3 tile-buffers, each A[256][64] + B[128][64] bf16 = 48 KB
// (total 144 KB). Chunk-XOR swizzle (slot = chunk ^ (row&7)) -> conflict-free
// ds_read_b128, staged via row-grouped global_load_lds with pre-swizzled src.
// Schedule per K-tile t: stage tile t+2 into buf[(t+2)%3] (last read at t-1,
// fenced by previous barrier), compute tile t, then
//   s_waitcnt vmcnt(6); s_barrier   <- tile t+1 landed, t+2 still in flight.
// Never drains vmcnt to 0 in steady state.
// MODE 0: fused QKV (N=6144; z=N0/2048 selects Q/K/V epilogue, rope from rtab)
// MODE 1: attn_out @ Wo^T, fp32 store.
// ---------------------------------------------------------------------------
template <int MODE>
__global__ __launch_bounds__(512, 2) void gemm_pipe(
    const unsigned short* __restrict__ A,
    const unsigned short* __restrict__ B,
    unsigned short* __restrict__ obf,   // MODE0: qb (kb=+NX, vb=+2NX)
    float* __restrict__ of32,           // MODE1: output
    const float2* __restrict__ rtab) {
  __shared__ unsigned short lds[3 * 24576];  // 147456 B
  const int nb = blockIdx.x, mb = blockIdx.y;
  const int M0 = mb * 256;
  const int t = threadIdx.x;
  const int w = t >> 6, lane = t & 63, l15 = lane & 15, quad = lane >> 4;
  const int g = lane >> 3, j = lane & 7;
  const int wm = w >> 1, wn = w & 1;

  const unsigned short* Abase = A + (size_t)M0 * DMODEL;
  const unsigned short* Bbase = B + (size_t)nb * 128 * DMODEL;

  f32x4 acc[4][4] = {};

  // stage 3 of this wave's 6 units for one tile. units: 0..31 A (8 rows each),
  // 32..47 B. dest linear [8 rows][8 chunks][16B]; src chunk pre-swizzled j^g.
  auto stage = [&](int buf, int k0, int i0) {
#pragma unroll
    for (int i = 0; i < 3; ++i) {
      const int u = w * 6 + i0 + i;
      if (u < 32) {
        const int row = u * 8 + g;
        g2l16(Abase + (size_t)row * DMODEL + k0 + ((j ^ g) << 3),
              &lds[buf * 24576 + u * 512]);
      } else {
        const int row = (u - 32) * 8 + g;
        g2l16(Bbase + (size_t)row * DMODEL + k0 + ((j ^ g) << 3),
              &lds[buf * 24576 + 16384 + (u - 32) * 512]);
      }
    }
  };

  // one kc half (K=32) of one tile: 8 ds_read_b128 + 16 MFMA
  auto comp = [&](int buf, int kc) {
    const int c = kc * 4 + quad;
    const unsigned short* As_ = &lds[buf * 24576];
    const unsigned short* Bs_ = &lds[buf * 24576 + 16384];
    bf16x8 af[4], bf[4];
#pragma unroll
    for (int mt = 0; mt < 4; ++mt) {
      const int m = wm * 64 + mt * 16 + l15;
      af[mt] = *(const bf16x8*)&As_[m * 64 + ((c ^ (m & 7)) << 3)];
    }
#pragma unroll
    for (int nt = 0; nt < 4; ++nt) {
      const int n = wn * 64 + nt * 16 + l15;
      bf[nt] = *(const bf16x8*)&Bs_[n * 64 + ((c ^ (n & 7)) << 3)];
    }
#pragma unroll
    for (int nt = 0; nt < 4; ++nt)
#pragma unroll
      for (int mt = 0; mt < 4; ++mt)
        acc[mt][nt] = mfma16(af[mt], bf[nt], acc[mt][nt]);
  };

  // prologue: tiles 0 and 1 in flight (12 loads); wait tile 0 (6 remain)
  stage(0, 0, 0);
  stage(0, 0, 3);
  stage(1, 64, 0);
  stage(1, 64, 3);
  asm volatile("s_waitcnt vmcnt(6)\n\ts_barrier" ::: "memory");

  int buf = 0, b2 = 2;
  for (int tt = 0; tt < 32; ++tt) {
    const int k0 = tt * 64;
    if (tt < 30) stage(b2, k0 + 128, 0);
    comp(buf, 0);
    if (tt < 30) stage(b2, k0 + 128, 3);
    comp(buf, 1);
    if (tt < 30) {
      asm volatile("s_waitcnt vmcnt(6)\n\ts_barrier" ::: "memory");
    } else if (tt == 30) {
      asm volatile("s_waitcnt vmcnt(0)\n\ts_barrier" ::: "memory");
    }
    buf = (buf == 2) ? 0 : buf + 1;
    b2 = (b2 == 2) ? 0 : b2 + 1;
  }

  // Epilogue. C/D layout: col = l15 (N side), row = quad*4 + reg (M side).
  if (MODE == 0) {
    const size_t NX = (size_t)2 * SEQ * DMODEL;
    const int z = nb >> 4;  // 0:Q 1:K 2:V (BN=128 == one head)
    const int h = nb & 15;
    if (z < 2) {
      // permuted layout: frag pair (2p, 2p+1) = (x1, x2), rotary dim
      // d = (wn*2+p)*16 + l15. Q also pre-scaled by log2e/sqrt(hd).
      const float qscale = (z == 0) ? 0.1275174356f : 1.0f;
      unsigned short* O = obf + (size_t)z * NX;
#pragma unroll
      for (int mt = 0; mt < 4; ++mt)
#pragma unroll
        for (int reg = 0; reg < 4; ++reg) {
          const int m = M0 + wm * 64 + mt * 16 + quad * 4 + reg;
          const int bb = m >> 11, s = m & 2047;
          unsigned short* ob = O + ((size_t)(bb * NH + h) * SEQ + s) * HD;
#pragma unroll
          for (int p = 0; p < 2; ++p) {
            const int q = wn * 2 + p;
            const float2 cs = rtab[s * 64 + q * 16 + l15];
            const float x1 = acc[mt][2 * p][reg], x2 = acc[mt][2 * p + 1][reg];
            ob[wn * 64 + (2 * p) * 16 + l15] = f2bf((x1 * cs.x - x2 * cs.y) * qscale);
            ob[wn * 64 + (2 * p + 1) * 16 + l15] = f2bf((x2 * cs.x + x1 * cs.y) * qscale);
          }
        }
    } else {
      // V stored transposed: (B,H,hd,S), natural (unpermuted) d
      unsigned short* Vb = obf + 2 * NX + (size_t)h * HD * SEQ;
#pragma unroll
      for (int mt = 0; mt < 4; ++mt)
#pragma unroll
        for (int reg = 0; reg < 4; ++reg) {
          const int m = M0 + wm * 64 + mt * 16 + quad * 4 + reg;
          const int bb = m >> 11, s = m & 2047;
          unsigned short* ob = Vb + (size_t)bb * NH * HD * SEQ;
#pragma unroll
          for (int nt = 0; nt < 4; ++nt)
            ob[(size_t)(wn * 64 + nt * 16 + l15) * SEQ + s] = f2bf(acc[mt][nt][reg]);
        }
    }
  } else {
#pragma unroll
    for (int mt = 0; mt < 4; ++mt)
#pragma unroll
      for (int reg = 0; reg < 4; ++reg) {
        const int m = M0 + wm * 64 + mt * 16 + quad * 4 + reg;
#pragma unroll
        for (int nt = 0; nt < 4; ++nt)
          of32[(size_t)m * DMODEL + nb * 128 + wn * 64 + nt * 16 + l15] =
              acc[mt][nt][reg];
      }
  }
}

// ---------------------------------------------------------------------------
// Flash attention, causal. Block = one (b,h), processes q-tiles p and 15-p
// sequentially: exactly 17 K-tile iterations per block (perfect balance).
// K/V staged with half-row (128B) swizzle. P round-trips through
// wave-private LDS. No min-wave launch bound -> no register spill.
// (unchanged from R3; Q/K head-dim permutation cancels inside the dot)
// ---------------------------------------------------------------------------
__global__ __launch_bounds__(256) void attn_kernel(const unsigned short* __restrict__ Q,
                                                   const unsigned short* __restrict__ K,
                                                   const unsigned short* __restrict__ Vt,
                                                   unsigned short* __restrict__ Oa) {
  __shared__ unsigned short Ks[256 * 64];  // 32 KB
  __shared__ unsigned short Vs[256 * 64];  // 32 KB
  const int gid = blockIdx.x;
  const int bh = gid & 31;   // bh = XCD-local: each XCD caches 4 bh's K+V (4MB)
  const int pr = gid >> 5;   // pair index 0..7
  const unsigned short* Qb = Q + (size_t)bh * SEQ * HD;
  const unsigned short* Kb = K + (size_t)bh * SEQ * HD;
  const unsigned short* Vb = Vt + (size_t)bh * HD * SEQ;
  const int t = threadIdx.x;
  const int w = t >> 6, lane = t & 63, l15 = lane & 15, quad = lane >> 4;
  const int g = lane >> 3, j = lane & 7;
  const int b = bh >> 4, h = bh & 15;

  for (int half = 0; half < 2; ++half) {
    const int qt = half ? 15 - pr : pr;

    // Q fragments: A-layout row = l15, k(hd) = ch*32 + quad*8
    bf16x8 qf[2][4];
#pragma unroll
    for (int mt = 0; mt < 2; ++mt)
#pragma unroll
      for (int ch = 0; ch < 4; ++ch)
        qf[mt][ch] = *(const bf16x8*)(Qb + (size_t)(qt * 128 + w * 32 + mt * 16 + l15) * HD +
                                      ch * 32 + quad * 8);

    f32x4 o[2][8] = {};
    float mrow[2][4], lrow[2][4];
#pragma unroll
    for (int mt = 0; mt < 2; ++mt)
#pragma unroll
      for (int reg = 0; reg < 4; ++reg) { mrow[mt][reg] = -1e30f; lrow[mt][reg] = 0.f; }

    for (int kt = 0; kt <= qt; ++kt) {
      __syncthreads();
#pragma unroll
      for (int r = 0; r < 16; ++r) {  // 64 units: 32 K + 32 V
        const int u = r * 4 + w;
        if (u < 32) {
          const int vrow = u * 8 + g, key = vrow >> 1;
          const int ck = j ^ (key & 7);
          g2l16(Kb + (size_t)(kt * 128 + key) * HD + (vrow & 1) * 64 + ck * 8, &Ks[u * 512]);
        } else {
          const int u2 = u - 32;
          const int vrow = u2 * 8 + g, d = vrow >> 1;
          const int cv = j ^ (d & 7);
          g2l16(Vb + (size_t)d * SEQ + kt * 128 + (vrow & 1) * 64 + cv * 8, &Vs[u2 * 512]);
        }
      }
      __syncthreads();

      // S = Q K^T (Q pre-scaled by log2e/sqrt(hd))
      f32x4 s[2][8] = {};
#pragma unroll
      for (int ch = 0; ch < 4; ++ch) {
        const int hh = ch >> 1, c = (ch & 1) * 4 + quad;
#pragma unroll
        for (int nt = 0; nt < 8; ++nt) {
          const int n = nt * 16 + l15;
          const bf16x8 bv = *(const bf16x8*)&Ks[(n * 2 + hh) * 64 + ((c ^ (n & 7)) << 3)];
#pragma unroll
          for (int mt = 0; mt < 2; ++mt) s[mt][nt] = mfma16(qf[mt][ch], bv, s[mt][nt]);
        }
      }

      if (kt == qt) {  // causal mask on diagonal tile
#pragma unroll
        for (int mt = 0; mt < 2; ++mt)
#pragma unroll
          for (int nt = 0; nt < 8; ++nt)
#pragma unroll
            for (int reg = 0; reg < 4; ++reg) {
              const int rr = w * 32 + mt * 16 + quad * 4 + reg;
              const int cc = nt * 16 + l15;
              if (cc > rr) s[mt][nt][reg] = -1e30f;
            }
      }

      // online softmax in log2 domain
#pragma unroll
      for (int mt = 0; mt < 2; ++mt)
#pragma unroll
        for (int reg = 0; reg < 4; ++reg) {
          float vmax = s[mt][0][reg];
#pragma unroll
          for (int nt = 1; nt < 8; ++nt) vmax = fmaxf(vmax, s[mt][nt][reg]);
          vmax = red_max16(vmax);
          const float mo = mrow[mt][reg];
          const float mn = fmaxf(mo, vmax);
          const float alpha = exp2f(mo - mn);
          mrow[mt][reg] = mn;
          float rs = 0.f;
#pragma unroll
          for (int nt = 0; nt < 8; ++nt) {
            const float p_ = exp2f(s[mt][nt][reg] - mn);
            s[mt][nt][reg] = p_;
            rs += p_;
          }
          rs = red_sum16(rs);
          lrow[mt][reg] = lrow[mt][reg] * alpha + rs;
#pragma unroll
          for (int nt = 0; nt < 8; ++nt) o[mt][nt][reg] *= alpha;
        }

      __syncthreads();  // all waves done reading Ks before P overwrites it

      unsigned short* Pw = &Ks[w * 4096];  // [16 key-planes][32 q-rows][8]
#pragma unroll
      for (int mt = 0; mt < 2; ++mt)
#pragma unroll
        for (int nt = 0; nt < 8; ++nt)
#pragma unroll
          for (int reg = 0; reg < 4; ++reg) {
            const int rr = mt * 16 + quad * 4 + reg;
            const int key = nt * 16 + l15;
            Pw[(key >> 3) * 256 + rr * 8 + (key & 7)] = f2bf(s[mt][nt][reg]);
          }

      // O += P V
#pragma unroll
      for (int ch = 0; ch < 4; ++ch) {
        const int kh = ch >> 1, c = (ch & 1) * 4 + quad;
        bf16x8 pa[2];
#pragma unroll
        for (int mt = 0; mt < 2; ++mt)
          pa[mt] = *(const bf16x8*)&Pw[(ch * 4 + quad) * 256 + (mt * 16 + l15) * 8];
#pragma unroll
        for (int nt = 0; nt < 8; ++nt) {
          const int d = nt * 16 + l15;
          const bf16x8 vv = *(const bf16x8*)&Vs[(d * 2 + kh) * 64 + ((c ^ (d & 7)) << 3)];
#pragma unroll
          for (int mt = 0; mt < 2; ++mt) o[mt][nt] = mfma16(pa[mt], vv, o[mt][nt]);
        }
      }
    }

    // epilogue: normalize and store attn output as (B*S, D) bf16
#pragma unroll
    for (int mt = 0; mt < 2; ++mt)
#pragma unroll
      for (int reg = 0; reg < 4; ++reg) {
        const int sq = qt * 128 + w * 32 + mt * 16 + quad * 4 + reg;
        const float inv_l = 1.0f / lrow[mt][reg];
        unsigned short* ob = Oa + (size_t)(b * SEQ + sq) * DMODEL + h * HD;
#pragma unroll
        for (int nt = 0; nt < 8; ++nt) ob[nt * 16 + l15] = f2bf(o[mt][nt][reg] * inv_l);
      }
  }
}

extern "C" void kernel_launch(void* const* d_in, const int* in_sizes, int n_in,
                              void* d_out, int out_size, void* d_ws, size_t ws_size,
                              hipStream_t stream) {
  const float* x = (const float*)d_in[0];
  const float* Wq = (const float*)d_in[1];
  const float* Wk = (const float*)d_in[2];
  const float* Wv = (const float*)d_in[3];
  const float* Wo = (const float*)d_in[4];
  float* out = (float*)d_out;

  const size_t NX = (size_t)2 * SEQ * DMODEL;
  const size_t NW = (size_t)DMODEL * DMODEL;
  unsigned short* ws = (unsigned short*)d_ws;
  unsigned short* xb = ws;
  unsigned short* wqb = xb + NX;   // wq/wk/wv contiguous -> fused N=6144 B operand
  unsigned short* wkb = wqb + NW;
  unsigned short* wvb = wkb + NW;
  unsigned short* wob = wvb + NW;
  unsigned short* qb = wob + NW;  // (B,H,S,hd) permuted-hd, rope'd, *log2e/sqrt(hd)
  unsigned short* kb = qb + NX;   // (B,H,S,hd) permuted-hd, rope'd
  unsigned short* vb = kb + NX;   // (B,H,hd,S)
  unsigned short* ab = vb + NX;   // (B*S, D)
  float2* rtab = (float2*)(ab + NX);  // 2048 x 64 cos/sin (1 MB)

  cvt_all<<<25088, 256, 0, stream>>>(x, Wq, Wk, Wv, Wo, ws, rtab);
  gemm_pipe<0><<<dim3(48, 16), 512, 0, stream>>>(xb, wqb, qb, nullptr, rtab);
  attn_kernel<<<256, 256, 0, stream>>>(qb, kb, vb, ab);
  gemm_pipe<1><<<dim3(16, 16), 512, 0, stream>>>(ab, wob, nullptr, out, nullptr);
}